// Round 6
// baseline (407.710 us; speedup 1.0000x reference)
//
#include <hip/hip_runtime.h>
#include <math.h>
#include <stdint.h>

// Problem constants (fixed by setup_inputs)
#define NTOK 16384      // B*S = 4*4096
#define SEQ  4096
#define HD   2048
#define MD   128
#define NCH  64         // number of chunks == N_SLOTS (ptr never wraps)
#define CHK  64         // chunk_size

typedef __attribute__((ext_vector_type(8))) _Float16 half8;  // 8 fp16 = 4 VGPRs
typedef __attribute__((ext_vector_type(4))) float floatx4;   // MFMA accumulator

__device__ __forceinline__ void gload_lds16(const void* g, void* l) {
    // async global->LDS, 16B per lane; LDS dest = wave-uniform base + lane*16
    __builtin_amdgcn_global_load_lds(
        (const __attribute__((address_space(1))) unsigned int*)(uintptr_t)g,
        (__attribute__((address_space(3))) unsigned int*)(uintptr_t)l,
        16, 0, 0);
}

// ---------------------------------------------------------------------------
// K0a: convert weights to fp16: Wcath = [Wq;Wk;Wv] (384 x 2048), Woh (2048x128)
// ---------------------------------------------------------------------------
__global__ __launch_bounds__(256) void convert_w_kernel(
    const float* __restrict__ Wq, const float* __restrict__ Wk,
    const float* __restrict__ Wv, const float* __restrict__ Wo,
    _Float16* __restrict__ Wcath, _Float16* __restrict__ Woh)
{
    int i = blockIdx.x * 256 + threadIdx.x;   // 0 .. 1048575
    if (i < 384 * HD) {
        int r = i >> 11;
        float val;
        if (r < 128)      val = Wq[i];
        else if (r < 256) val = Wk[i - 128 * HD];
        else              val = Wv[i - 256 * HD];
        Wcath[i] = (_Float16)val;
    } else {
        int j = i - 384 * HD;                 // 0 .. 262143
        Woh[j] = (_Float16)Wo[j];
    }
}

// ---------------------------------------------------------------------------
// K0b: G = W_out^T @ W_out (128x128) in f32 (for the output-norm clamp)
// ---------------------------------------------------------------------------
__global__ __launch_bounds__(128) void gmat_kernel(
    const float* __restrict__ Wo, float* __restrict__ G)
{
    __shared__ float col[HD];
    int a = blockIdx.x;
    int b = threadIdx.x;
    for (int j = b; j < HD; j += 128) col[j] = Wo[(size_t)j * MD + a];
    __syncthreads();
    float s = 0.f;
    for (int j = 0; j < HD; ++j) s = fmaf(col[j], Wo[(size_t)j * MD + b], s);
    G[a * MD + b] = s;
}

// ---------------------------------------------------------------------------
// K1 v5: merged proj GEMM + FUSED normsig + agg_part epilogue.
//   Core (= v4): one block computes q,k,v (all 384 cols) for its 64-row
//   x tile; BK=64, double-buffered LDS, one barrier per K-step, async B
//   staging (pre-swizzled source, rule 21), A regs issue-early/write-late,
//   XOR swizzle ((row&7)<<4). 112 KB LDS -> 1 block/CU.
//   Epilogue (new): a 64-row tile IS one (batch,chunk). k,v stay on-chip:
//   acc -> LDS (overlaying Bs after the last barrier), per-row l2norm
//   (exact normsig order), then per-chunk weighted aggregation (exact
//   agg_part order) -> kpart/vpart/wpart. kn,vn,wg never hit global.
// grid (256), 256 threads, tile 64 x (3x128), mfma 16x16x32 f16.
// ---------------------------------------------------------------------------
__global__ __launch_bounds__(256, 1) void gemm_proj_mfma(
    const float* __restrict__ x, const _Float16* __restrict__ Wcath,
    const float* __restrict__ Wgw, const float* __restrict__ gb,
    float* __restrict__ q,
    float* __restrict__ kpart, float* __restrict__ vpart,
    float* __restrict__ wpart)
{
    __shared__ _Float16 As[2][64 * 64];        // 8 KB per buffer
    __shared__ _Float16 Bs[2][3][128 * 64];    // 16 KB per panel per buffer
    floatx4 acc[3][2][4];
    #pragma unroll
    for (int p = 0; p < 3; ++p)
        #pragma unroll
        for (int i = 0; i < 2; ++i)
            #pragma unroll
            for (int j = 0; j < 4; ++j) acc[p][i][j] = (floatx4){0.f, 0.f, 0.f, 0.f};

    const int tid  = threadIdx.x;
    const int wave = tid >> 6, lane = tid & 63;
    const int wm = wave & 1, wn = wave >> 1;   // wave -> 32-row half x 64-col half
    const int row0 = blockIdx.x * 64;

    const int ar0 = tid >> 3;                 // rows 0..31 ; second row = ar0+32
    const int ac0 = (tid & 7) ^ (ar0 & 7);    // pre-swizzled 8-f32 column group
    const float* xA0 = x + (size_t)(row0 + ar0) * HD + ac0 * 8;
    const float* xA1 = x + (size_t)(row0 + ar0 + 32) * HD + ac0 * 8;
    const float* wgp = Wgw + ac0 * 8;

    float gacc0 = 0.f, gacc1 = 0.f;
    float4 a00, a01, a10, a11, g0, g1;

#define STAGE_B(buf_, k0_) do {                                               \
        _Pragma("unroll")                                                     \
        for (int p = 0; p < 3; ++p) {                                         \
            _Pragma("unroll")                                                 \
            for (int rnd = 0; rnd < 4; ++rnd) {                               \
                int sg = rnd * 4 + wave;                                      \
                int br = sg * 8 + (lane >> 3);                                \
                int bc = (lane & 7) ^ (br & 7);                               \
                gload_lds16(Wcath + (size_t)(p * 128 + br) * HD + (k0_) + bc * 8, \
                            (char*)Bs[buf_][p] + sg * 1024);                  \
            }                                                                 \
        } } while (0)

#define LOAD_A(k0_) do {                                                      \
        a00 = *(const float4*)(xA0 + (k0_));                                  \
        a01 = *(const float4*)(xA0 + (k0_) + 4);                              \
        a10 = *(const float4*)(xA1 + (k0_));                                  \
        a11 = *(const float4*)(xA1 + (k0_) + 4);                              \
        g0 = *(const float4*)(wgp + (k0_));                                   \
        g1 = *(const float4*)(wgp + (k0_) + 4);                               \
    } while (0)

#define FINISH_A(buf_) do {                                                   \
        gacc0 += a00.x*g0.x + a00.y*g0.y + a00.z*g0.z + a00.w*g0.w            \
               + a01.x*g1.x + a01.y*g1.y + a01.z*g1.z + a01.w*g1.w;           \
        gacc1 += a10.x*g0.x + a10.y*g0.y + a10.z*g0.z + a10.w*g0.w            \
               + a11.x*g1.x + a11.y*g1.y + a11.z*g1.z + a11.w*g1.w;           \
        half8 h0, h1;                                                         \
        h0[0] = (_Float16)a00.x; h0[1] = (_Float16)a00.y;                     \
        h0[2] = (_Float16)a00.z; h0[3] = (_Float16)a00.w;                     \
        h0[4] = (_Float16)a01.x; h0[5] = (_Float16)a01.y;                     \
        h0[6] = (_Float16)a01.z; h0[7] = (_Float16)a01.w;                     \
        h1[0] = (_Float16)a10.x; h1[1] = (_Float16)a10.y;                     \
        h1[2] = (_Float16)a10.z; h1[3] = (_Float16)a10.w;                     \
        h1[4] = (_Float16)a11.x; h1[5] = (_Float16)a11.y;                     \
        h1[6] = (_Float16)a11.z; h1[7] = (_Float16)a11.w;                     \
        *(half8*)((char*)As[buf_] + tid * 16)        = h0;                    \
        *(half8*)((char*)As[buf_] + 4096 + tid * 16) = h1;                    \
    } while (0)

#define COMPUTE(buf_) do {                                                    \
        half8 af[2][2];                                                       \
        _Pragma("unroll")                                                     \
        for (int i = 0; i < 2; ++i) {                                         \
            int r  = wm * 32 + i * 16 + (lane & 15);                          \
            int rb = r * 128 + (lane >> 4) * 16;                              \
            int sw = (r & 7) << 4;                                            \
            af[i][0] = *(const half8*)((const char*)As[buf_] + ( rb       ^ sw)); \
            af[i][1] = *(const half8*)((const char*)As[buf_] + ((rb + 64) ^ sw)); \
        }                                                                     \
        _Pragma("unroll")                                                     \
        for (int p = 0; p < 3; ++p) {                                         \
            half8 bf[4][2];                                                   \
            _Pragma("unroll")                                                 \
            for (int j = 0; j < 4; ++j) {                                     \
                int r  = wn * 64 + j * 16 + (lane & 15);                      \
                int rb = r * 128 + (lane >> 4) * 16;                          \
                int sw = (r & 7) << 4;                                        \
                bf[j][0] = *(const half8*)((const char*)Bs[buf_][p] + ( rb       ^ sw)); \
                bf[j][1] = *(const half8*)((const char*)Bs[buf_][p] + ((rb + 64) ^ sw)); \
            }                                                                 \
            _Pragma("unroll")                                                 \
            for (int ks = 0; ks < 2; ++ks)                                    \
                _Pragma("unroll")                                             \
                for (int i = 0; i < 2; ++i)                                   \
                    _Pragma("unroll")                                         \
                    for (int j = 0; j < 4; ++j)                               \
                        acc[p][i][j] = __builtin_amdgcn_mfma_f32_16x16x32_f16(\
                            af[i][ks], bf[j][ks], acc[p][i][j], 0, 0, 0);     \
        }                                                                     \
    } while (0)

    STAGE_B(0, 0);
    LOAD_A(0);
    FINISH_A(0);
    __syncthreads();

    int cur = 0;
    for (int t = 0; t < HD / 64; ++t) {
        if (t < HD / 64 - 1) {
            STAGE_B(cur ^ 1, (t + 1) * 64);   // async, drains at the barrier
            LOAD_A((t + 1) * 64);             // regs, consumed after MFMA
        }
        COMPUTE(cur);
        if (t < HD / 64 - 1) FINISH_A(cur ^ 1);
        __syncthreads();
        cur ^= 1;
    }
    // last barrier passed: all waves done with As/Bs -> safe to overlay.

    // ---- LDS overlays for the fused epilogue ----
    float* k_s   = (float*)&Bs[0][0][0];      // 64 x 128 f32 = 32 KB
    float* v_s   = k_s + 64 * 128;            // 32 KB (total 64 <= 96 KB)
    float* ws_s  = (float*)&As[0][0];         // 64 f32 gate values
    float* red_s = ws_s + 64;                 // 2 x 128 f32 half-combine

    // ---- q store (global) ----
    #pragma unroll
    for (int i = 0; i < 2; ++i) {
        int m = row0 + wm * 32 + i * 16 + (lane >> 4) * 4;
        #pragma unroll
        for (int j = 0; j < 4; ++j) {
            int c = wn * 64 + j * 16 + (lane & 15);
            #pragma unroll
            for (int r = 0; r < 4; ++r)
                q[(size_t)(m + r) * MD + c] = acc[0][i][j][r];
        }
    }

    // ---- gate values -> ws_s (exact same reduction as before) ----
    gacc0 += __shfl_xor(gacc0, 1);
    gacc0 += __shfl_xor(gacc0, 2);
    gacc0 += __shfl_xor(gacc0, 4);
    gacc1 += __shfl_xor(gacc1, 1);
    gacc1 += __shfl_xor(gacc1, 2);
    gacc1 += __shfl_xor(gacc1, 4);
    if ((tid & 7) == 0) {
        ws_s[ar0]      = 1.f / (1.f + expf(-(gacc0 + gb[0])));
        ws_s[ar0 + 32] = 1.f / (1.f + expf(-(gacc1 + gb[0])));
    }

    // ---- k, v accumulators -> LDS (local row index 0..63) ----
    #pragma unroll
    for (int i = 0; i < 2; ++i) {
        int m = wm * 32 + i * 16 + (lane >> 4) * 4;
        #pragma unroll
        for (int j = 0; j < 4; ++j) {
            int c = wn * 64 + j * 16 + (lane & 15);
            #pragma unroll
            for (int r = 0; r < 4; ++r) {
                k_s[(m + r) * 128 + c] = acc[1][i][j][r];
                v_s[(m + r) * 128 + c] = acc[2][i][j][r];
            }
        }
    }
    __syncthreads();

    // ---- per-row l2norm (replicates normsig: lane owns dims 2l, 2l+1,
    //      full 64-lane xor tree, same op order) ----
    #pragma unroll
    for (int rr = 0; rr < 16; ++rr) {
        int row = wave * 16 + rr;
        float kx = k_s[row * 128 + 2 * lane];
        float ky = k_s[row * 128 + 2 * lane + 1];
        float vx = v_s[row * 128 + 2 * lane];
        float vy = v_s[row * 128 + 2 * lane + 1];
        float ks = kx * kx + ky * ky;
        float vs = vx * vx + vy * vy;
        #pragma unroll
        for (int off = 32; off > 0; off >>= 1) {
            ks += __shfl_xor(ks, off);
            vs += __shfl_xor(vs, off);
        }
        float ki = 1.f / fmaxf(sqrtf(ks), 1e-12f);
        float vi = 1.f / fmaxf(sqrtf(vs), 1e-12f);
        k_s[row * 128 + 2 * lane]     = kx * ki;
        k_s[row * 128 + 2 * lane + 1] = ky * ki;
        v_s[row * 128 + 2 * lane]     = vx * vi;
        v_s[row * 128 + 2 * lane + 1] = vy * vi;
    }
    __syncthreads();

    // ---- per-chunk weighted aggregation (replicates agg_part exactly) ----
    {
        const int d = tid & 127, h = tid >> 7;
        float ka = 0.f, va = 0.f;
        for (int c = h * 32; c < h * 32 + 32; ++c) {
            float wv = ws_s[c];
            ka = fmaf(wv, k_s[c * 128 + d], ka);
            va = fmaf(wv, v_s[c * 128 + d], va);
        }
        if (h == 1) { red_s[d] = ka; red_s[128 + d] = va; }
        __syncthreads();
        const int bidx = ((row0 & (SEQ - 1)) >> 6) * 4 + (row0 >> 12);  // t*4+b
        if (h == 0) {
            kpart[(size_t)bidx * 128 + d] = ka + red_s[d];
            vpart[(size_t)bidx * 128 + d] = va + red_s[128 + d];
        }
        if (tid < 64) {
            float wv = ws_s[tid];
            #pragma unroll
            for (int off = 32; off > 0; off >>= 1) wv += __shfl_xor(wv, off);
            if (tid == 0) wpart[bidx] = wv;
        }
    }
#undef STAGE_B
#undef LOAD_A
#undef FINISH_A
#undef COMPUTE
}

// ---------------------------------------------------------------------------
// K2b: combine partials per chunk, normalize, emit kaT / vagg / wstr.
// grid 64, 128 threads (2 waves)
// ---------------------------------------------------------------------------
__global__ __launch_bounds__(128) void agg_combine_kernel(
    const float* __restrict__ kpart, const float* __restrict__ vpart,
    const float* __restrict__ wpart,
    float* __restrict__ kaT, float* __restrict__ vagg, float* __restrict__ wstr)
{
    int t = blockIdx.x;
    int d = threadIdx.x;              // 0..127
    int wave = d >> 6, lane = d & 63;
    float ku = 0.f, vu = 0.f;
    #pragma unroll
    for (int b = 0; b < 4; ++b) {
        ku += kpart[(size_t)(t * 4 + b) * 128 + d];
        vu += vpart[(size_t)(t * 4 + b) * 128 + d];
    }
    float wsum = wpart[t * 4] + wpart[t * 4 + 1] + wpart[t * 4 + 2] + wpart[t * 4 + 3];
    float winv = 1.f / fmaxf(wsum, 1e-8f);
    ku *= winv; vu *= winv;

    __shared__ float red[4];
    float ks = ku * ku, vs = vu * vu;
    #pragma unroll
    for (int off = 32; off > 0; off >>= 1) {
        ks += __shfl_xor(ks, off);
        vs += __shfl_xor(vs, off);
    }
    if (lane == 0) { red[wave] = ks; red[2 + wave] = vs; }
    __syncthreads();
    float kinv = 1.f / fmaxf(sqrtf(red[0] + red[1]), 1e-12f);
    float vinv = 1.f / fmaxf(sqrtf(red[2] + red[3]), 1e-12f);
    kaT[d * NCH + t] = ku * kinv;
    vagg[t * MD + d] = vu * vinv;
    if (d == 0) wstr[t] = wsum * (1.f / 256.f);
}

// ---------------------------------------------------------------------------
// K2c: mean_ws -> last element of d_out
// ---------------------------------------------------------------------------
__global__ __launch_bounds__(64) void meanws_kernel(
    const float* __restrict__ wstr, float* __restrict__ outp)
{
    int lane = threadIdx.x;
    float v = wstr[lane];
    #pragma unroll
    for (int off = 32; off > 0; off >>= 1) v += __shfl_xor(v, off);
    if (lane == 0) outp[0] = v * (1.f / 64.f);
}

// ---------------------------------------------------------------------------
// K3 v2: causal slot attention + G-norm scale; writes r (fp16) for out GEMM.
//   256 blocks (1/CU), 512 threads (8 waves), 64 rows/block; kaT+vagg+G
//   staged once into 128 KB LDS. Arithmetic order identical to v1.
// ---------------------------------------------------------------------------
__global__ __launch_bounds__(512, 1) void attn_kernel(
    const float* __restrict__ q, const float* __restrict__ kaT,
    const float* __restrict__ vagg, const float* __restrict__ G,
    const float* __restrict__ logbeta, _Float16* __restrict__ rsh16)
{
    __shared__ float kaT_s[MD * NCH];     // 32 KB [d][slot]
    __shared__ float vagg_s[NCH * MD];    // 32 KB [slot][d]
    __shared__ float G_s[MD * MD];        // 64 KB [b][d]
    __shared__ float qs[8][MD];           // 4 KB per-wave scratch
    __shared__ float attn_sh[8][64];      // 2 KB
    __shared__ float rsh_sh[8][MD];       // 4 KB   (total 138 KB)

    const int tid  = threadIdx.x;
    const int wave = tid >> 6, lane = tid & 63;
    const int row0 = blockIdx.x * 64;
    const int t = (row0 & (SEQ - 1)) >> 6;      // uniform for the whole block
    const float beta = expf(logbeta[0]);

    {
        const float4* s0 = (const float4*)kaT;
        const float4* s1 = (const float4*)vagg;
        const float4* s2 = (const float4*)G;
        float4* d0 = (float4*)kaT_s;
        float4* d1 = (float4*)vagg_s;
        float4* d2 = (float4*)G_s;
        #pragma unroll
        for (int i = 0; i < 4; ++i) {
            d0[tid + i * 512] = s0[tid + i * 512];
            d1[tid + i * 512] = s1[tid + i * 512];
        }
        #pragma unroll
        for (int i = 0; i < 8; ++i)
            d2[tid + i * 512] = s2[tid + i * 512];
    }
    __syncthreads();

    for (int rr = 0; rr < 8; ++rr) {
        const int row = row0 + wave * 8 + rr;
        float q0 = q[(size_t)row * MD + lane];
        float q1 = q[(size_t)row * MD + 64 + lane];
        qs[wave][lane]      = q0;
        qs[wave][lane + 64] = q1;   // wave-local: lgkmcnt ordering, no barrier

        float sc = -INFINITY;
        if (lane < t) {
            sc = 0.f;
            for (int d = 0; d < 128; ++d)
                sc = fmaf(qs[wave][d], kaT_s[d * NCH + lane], sc);
            sc *= beta;
        }
        float mx = sc;
        #pragma unroll
        for (int off = 32; off > 0; off >>= 1) mx = fmaxf(mx, __shfl_xor(mx, off));
        float e = (lane < t) ? expf(sc - mx) : 0.f;
        float ssum = e;
        #pragma unroll
        for (int off = 32; off > 0; off >>= 1) ssum += __shfl_xor(ssum, off);
        float attn = (t > 0) ? (e / ssum) : 0.f;
        attn_sh[wave][lane] = attn;

        float r0 = 0.f, r1 = 0.f;
        for (int n = 0; n < t; ++n) {
            float a = attn_sh[wave][n];
            r0 = fmaf(a, vagg_s[n * MD + lane], r0);
            r1 = fmaf(a, vagg_s[n * MD + 64 + lane], r1);
        }
        rsh_sh[wave][lane]      = r0;
        rsh_sh[wave][lane + 64] = r1;

        float t0 = 0.f, t1 = 0.f;
        for (int b = 0; b < 128; ++b) {
            float rb = rsh_sh[wave][b];
            t0 = fmaf(G_s[b * MD + lane], rb, t0);
            t1 = fmaf(G_s[b * MD + 64 + lane], rb, t1);
        }
        float quad = r0 * t0 + r1 * t1;
        #pragma unroll
        for (int off = 32; off > 0; off >>= 1) quad += __shfl_xor(quad, off);
        float nrm = fmaxf(sqrtf(fmaxf(quad, 0.f)), 1e-6f);
        float scl = fminf(10.f / nrm, 1.f);
        rsh16[(size_t)row * MD + lane]      = (_Float16)(r0 * scl);
        rsh16[(size_t)row * MD + 64 + lane] = (_Float16)(r1 * scl);
    }
}

// ---------------------------------------------------------------------------
// K4 v2: out = rsh16 @ Woh^T  (16384x128)@(2048x128)^T -> f32 (16384x2048)
//   Single-shot K=128, one barrier, swizzled via pre-swizzled global source.
// grid (128, 16), 256 threads
// ---------------------------------------------------------------------------
__global__ __launch_bounds__(256) void gemm_out_mfma(
    const _Float16* __restrict__ rsh16, const _Float16* __restrict__ Woh,
    float* __restrict__ C)
{
    __shared__ _Float16 As[128 * 128];   // 32 KB, 256 B rows, swizzled slots
    __shared__ _Float16 Bs[128 * 128];   // 32 KB
    floatx4 acc[4][4];
    #pragma unroll
    for (int i = 0; i < 4; ++i)
        #pragma unroll
        for (int j = 0; j < 4; ++j) acc[i][j] = (floatx4){0.f, 0.f, 0.f, 0.f};

    const int tid  = threadIdx.x;
    const int wave = tid >> 6, lane = tid & 63;
    const int wm = wave & 1, wn = wave >> 1;
    const int row0 = blockIdx.x * 128;
    const int col0 = blockIdx.y * 128;

    const int sr = lane >> 4;            // row within 4-row segment
    const int sp = lane & 15;            // physical 16B slot
    #pragma unroll
    for (int rnd = 0; rnd < 8; ++rnd) {
        int seg = wave * 8 + rnd;        // 0..31 (4 rows each)
        int r = seg * 4 + sr;            // 0..127
        int c = sp ^ (r & 15);           // source slot (swizzle pre-applied)
        gload_lds16(rsh16 + (size_t)(row0 + r) * MD + c * 8,
                    (char*)As + seg * 1024);
        gload_lds16(Woh + (size_t)(col0 + r) * MD + c * 8,
                    (char*)Bs + seg * 1024);
    }
    __syncthreads();

    #pragma unroll
    for (int kf = 0; kf < 4; ++kf) {
        half8 af[4], bf[4];
        #pragma unroll
        for (int i = 0; i < 4; ++i) {
            int r = wm * 64 + i * 16 + (lane & 15);
            int g = kf * 4 + (lane >> 4);
            af[i] = *(const half8*)((const char*)As + r * 256 + ((g ^ (r & 15)) * 16));
        }
        #pragma unroll
        for (int j = 0; j < 4; ++j) {
            int r = wn * 64 + j * 16 + (lane & 15);
            int g = kf * 4 + (lane >> 4);
            bf[j] = *(const half8*)((const char*)Bs + r * 256 + ((g ^ (r & 15)) * 16));
        }
        #pragma unroll
        for (int i = 0; i < 4; ++i)
            #pragma unroll
            for (int j = 0; j < 4; ++j)
                acc[i][j] = __builtin_amdgcn_mfma_f32_16x16x32_f16(
                    af[i], bf[j], acc[i][j], 0, 0, 0);
    }

    #pragma unroll
    for (int i = 0; i < 4; ++i) {
        int m = row0 + wm * 64 + i * 16 + (lane >> 4) * 4;
        #pragma unroll
        for (int j = 0; j < 4; ++j) {
            int c = col0 + wn * 64 + j * 16 + (lane & 15);
            #pragma unroll
            for (int r = 0; r < 4; ++r)
                C[(size_t)(m + r) * HD + c] = acc[i][j][r];
        }
    }
}

// ---------------------------------------------------------------------------
extern "C" void kernel_launch(void* const* d_in, const int* in_sizes, int n_in,
                              void* d_out, int out_size, void* d_ws, size_t ws_size,
                              hipStream_t stream)
{
    const float* x   = (const float*)d_in[0];   // (4,4096,2048)
    const float* Wq  = (const float*)d_in[1];   // (128,2048)
    const float* Wk  = (const float*)d_in[2];
    const float* Wv  = (const float*)d_in[3];
    const float* Wo  = (const float*)d_in[4];   // (2048,128)
    const float* Wgw = (const float*)d_in[5];   // (1,2048)
    const float* Wgb = (const float*)d_in[6];   // (1,)
    const float* lb  = (const float*)d_in[7];   // (1,)
    float* out = (float*)d_out;                 // 16384*2048 + 1

    // workspace layout (16B-aligned throughout; kn/vn/wg slots retained but unused)
    float* q    = (float*)d_ws;                            // 2,097,152 f32
    float* kn   = q + (size_t)NTOK * MD;                   // (unused)
    float* vn   = kn + (size_t)NTOK * MD;                  // (unused)
    float* wg   = vn + (size_t)NTOK * MD;                  // (unused)
    float* kaT  = wg + NTOK;                               // 8192
    float* vagg = kaT + MD * NCH;                          // 8192
    float* wstr = vagg + NCH * MD;                         // 64
    float* G    = wstr + 64;                               // 16384
    float* kpart = G + MD * MD;                            // 32768
    float* vpart = kpart + 256 * 128;                      // 32768
    float* wpart = vpart + 256 * 128;                      // 256
    _Float16* Wcath = (_Float16*)(wpart + 256);            // 786,432 fp16
    _Float16* Woh   = Wcath + 384 * HD;                    // 262,144 fp16
    _Float16* rsh16 = Woh + HD * MD;                       // 2,097,152 fp16

    convert_w_kernel<<<dim3(4096), dim3(256), 0, stream>>>(Wq, Wk, Wv, Wo, Wcath, Woh);
    gmat_kernel<<<dim3(128), dim3(128), 0, stream>>>(Wo, G);
    gemm_proj_mfma<<<dim3(NTOK / 64), dim3(256), 0, stream>>>(
        x, Wcath, Wgw, Wgb, q, kpart, vpart, wpart);
    agg_combine_kernel<<<dim3(NCH), dim3(128), 0, stream>>>(kpart, vpart, wpart, kaT, vagg, wstr);
    meanws_kernel<<<dim3(1), dim3(64), 0, stream>>>(wstr, out + (size_t)NTOK * HD);
    attn_kernel<<<dim3(NTOK / 64), dim3(512), 0, stream>>>(q, kaT, vagg, G, lb, rsh16);
    gemm_out_mfma<<<dim3(NTOK / 128, HD / 128), dim3(256), 0, stream>>>(rsh16, Woh, out);
}

// Round 7
// 383.437 us; speedup vs baseline: 1.0633x; 1.0633x over previous
//
#include <hip/hip_runtime.h>
#include <math.h>
#include <stdint.h>

// Problem constants (fixed by setup_inputs)
#define NTOK 16384      // B*S = 4*4096
#define SEQ  4096
#define HD   2048
#define MD   128
#define NCH  64         // number of chunks == N_SLOTS (ptr never wraps)
#define CHK  64         // chunk_size

typedef __attribute__((ext_vector_type(8))) _Float16 half8;  // 8 fp16 = 4 VGPRs
typedef __attribute__((ext_vector_type(4))) float floatx4;   // MFMA accumulator

__device__ __forceinline__ void gload_lds16(const void* g, void* l) {
    // async global->LDS, 16B per lane; LDS dest = wave-uniform base + lane*16
    __builtin_amdgcn_global_load_lds(
        (const __attribute__((address_space(1))) unsigned int*)(uintptr_t)g,
        (__attribute__((address_space(3))) unsigned int*)(uintptr_t)l,
        16, 0, 0);
}

// ---------------------------------------------------------------------------
// K0a: convert weights to fp16: Wcath = [Wq;Wk;Wv] (384 x 2048), Woh (2048x128)
// ---------------------------------------------------------------------------
__global__ __launch_bounds__(256) void convert_w_kernel(
    const float* __restrict__ Wq, const float* __restrict__ Wk,
    const float* __restrict__ Wv, const float* __restrict__ Wo,
    _Float16* __restrict__ Wcath, _Float16* __restrict__ Woh)
{
    int i = blockIdx.x * 256 + threadIdx.x;   // 0 .. 1048575
    if (i < 384 * HD) {
        int r = i >> 11;
        float val;
        if (r < 128)      val = Wq[i];
        else if (r < 256) val = Wk[i - 128 * HD];
        else              val = Wv[i - 256 * HD];
        Wcath[i] = (_Float16)val;
    } else {
        int j = i - 384 * HD;                 // 0 .. 262143
        Woh[j] = (_Float16)Wo[j];
    }
}

// ---------------------------------------------------------------------------
// K0b: G = W_out^T @ W_out (128x128) in f32 (for the output-norm clamp)
// ---------------------------------------------------------------------------
__global__ __launch_bounds__(128) void gmat_kernel(
    const float* __restrict__ Wo, float* __restrict__ G)
{
    __shared__ float col[HD];
    int a = blockIdx.x;
    int b = threadIdx.x;
    for (int j = b; j < HD; j += 128) col[j] = Wo[(size_t)j * MD + a];
    __syncthreads();
    float s = 0.f;
    for (int j = 0; j < HD; ++j) s = fmaf(col[j], Wo[(size_t)j * MD + b], s);
    G[a * MD + b] = s;
}

// ---------------------------------------------------------------------------
// K1 v6: proj GEMM (= verified v3 structure, grid (256,3), 3 blocks/CU)
//   with fused per-row l2norm for the k/v panels (y=1/y=2): each block owns
//   all 128 cols of its 64 rows, so the row norm is block-local. acc -> LDS
//   overlay (32 KB of Bs, after the final barrier), then the EXACT normsig
//   arithmetic (lane owns dims 2l/2l+1, full 64-lane xor tree) and the
//   normalized k/v go straight to global. normsig kernel eliminated.
//   Occupancy stays 3 blocks/CU (48 KB LDS) — the R5/R6 1-block/CU merge
//   regressed and is reverted.
// ---------------------------------------------------------------------------
__global__ __launch_bounds__(256, 3) void gemm_proj_mfma(
    const float* __restrict__ x, const _Float16* __restrict__ Wcath,
    const float* __restrict__ Wgw, const float* __restrict__ gb,
    float* __restrict__ q, float* __restrict__ k, float* __restrict__ v,
    float* __restrict__ wg)
{
    __shared__ _Float16 As[2][64 * 64];    // 8 KB per buffer
    __shared__ _Float16 Bs[2][128 * 64];   // 16 KB per buffer
    floatx4 acc[2][4];
    #pragma unroll
    for (int i = 0; i < 2; ++i)
        #pragma unroll
        for (int j = 0; j < 4; ++j) acc[i][j] = (floatx4){0.f, 0.f, 0.f, 0.f};

    const int tid  = threadIdx.x;
    const int wave = tid >> 6, lane = tid & 63;
    const int wm = wave & 1, wn = wave >> 1;   // wave -> 32-row half x 64-col half
    const int row0 = blockIdx.x * 64;
    const int col0 = blockIdx.y * 128;
    const bool do_gate = (blockIdx.y == 0);

    const int ar0 = tid >> 3;                 // rows 0..31 ; second row = ar0+32
    const int ac0 = (tid & 7) ^ (ar0 & 7);    // pre-swizzled 8-f32 column group
    const float* xA0 = x + (size_t)(row0 + ar0) * HD + ac0 * 8;
    const float* xA1 = x + (size_t)(row0 + ar0 + 32) * HD + ac0 * 8;
    const float* wgp = Wgw + ac0 * 8;

    float gacc0 = 0.f, gacc1 = 0.f;
    float4 a00, a01, a10, a11, g0, g1;

#define STAGE_B(buf_, k0_) do {                                               \
        _Pragma("unroll")                                                     \
        for (int rnd = 0; rnd < 4; ++rnd) {                                   \
            int sg = rnd * 4 + wave;                                          \
            int br = sg * 8 + (lane >> 3);                                    \
            int bc = (lane & 7) ^ (br & 7);                                   \
            gload_lds16(Wcath + (size_t)(col0 + br) * HD + (k0_) + bc * 8,    \
                        (char*)Bs[buf_] + sg * 1024);                         \
        } } while (0)

#define LOAD_A(k0_) do {                                                      \
        a00 = *(const float4*)(xA0 + (k0_));                                  \
        a01 = *(const float4*)(xA0 + (k0_) + 4);                              \
        a10 = *(const float4*)(xA1 + (k0_));                                  \
        a11 = *(const float4*)(xA1 + (k0_) + 4);                              \
        if (do_gate) {                                                        \
            g0 = *(const float4*)(wgp + (k0_));                               \
            g1 = *(const float4*)(wgp + (k0_) + 4);                           \
        } } while (0)

#define FINISH_A(buf_) do {                                                   \
        if (do_gate) {                                                        \
            gacc0 += a00.x*g0.x + a00.y*g0.y + a00.z*g0.z + a00.w*g0.w        \
                   + a01.x*g1.x + a01.y*g1.y + a01.z*g1.z + a01.w*g1.w;       \
            gacc1 += a10.x*g0.x + a10.y*g0.y + a10.z*g0.z + a10.w*g0.w        \
                   + a11.x*g1.x + a11.y*g1.y + a11.z*g1.z + a11.w*g1.w;       \
        }                                                                     \
        half8 h0, h1;                                                         \
        h0[0] = (_Float16)a00.x; h0[1] = (_Float16)a00.y;                     \
        h0[2] = (_Float16)a00.z; h0[3] = (_Float16)a00.w;                     \
        h0[4] = (_Float16)a01.x; h0[5] = (_Float16)a01.y;                     \
        h0[6] = (_Float16)a01.z; h0[7] = (_Float16)a01.w;                     \
        h1[0] = (_Float16)a10.x; h1[1] = (_Float16)a10.y;                     \
        h1[2] = (_Float16)a10.z; h1[3] = (_Float16)a10.w;                     \
        h1[4] = (_Float16)a11.x; h1[5] = (_Float16)a11.y;                     \
        h1[6] = (_Float16)a11.z; h1[7] = (_Float16)a11.w;                     \
        *(half8*)((char*)As[buf_] + tid * 16)        = h0;                    \
        *(half8*)((char*)As[buf_] + 4096 + tid * 16) = h1;                    \
    } while (0)

#define COMPUTE(buf_) do {                                                    \
        half8 af[2][2], bf[4][2];                                             \
        _Pragma("unroll")                                                     \
        for (int i = 0; i < 2; ++i) {                                         \
            int r  = wm * 32 + i * 16 + (lane & 15);                          \
            int rb = r * 128 + (lane >> 4) * 16;                              \
            int sw = (r & 7) << 4;                                            \
            af[i][0] = *(const half8*)((const char*)As[buf_] + ( rb       ^ sw)); \
            af[i][1] = *(const half8*)((const char*)As[buf_] + ((rb + 64) ^ sw)); \
        }                                                                     \
        _Pragma("unroll")                                                     \
        for (int j = 0; j < 4; ++j) {                                         \
            int r  = wn * 64 + j * 16 + (lane & 15);                          \
            int rb = r * 128 + (lane >> 4) * 16;                              \
            int sw = (r & 7) << 4;                                            \
            bf[j][0] = *(const half8*)((const char*)Bs[buf_] + ( rb       ^ sw)); \
            bf[j][1] = *(const half8*)((const char*)Bs[buf_] + ((rb + 64) ^ sw)); \
        }                                                                     \
        _Pragma("unroll")                                                     \
        for (int ks = 0; ks < 2; ++ks)                                        \
            _Pragma("unroll")                                                 \
            for (int i = 0; i < 2; ++i)                                       \
                _Pragma("unroll")                                             \
                for (int j = 0; j < 4; ++j)                                   \
                    acc[i][j] = __builtin_amdgcn_mfma_f32_16x16x32_f16(       \
                        af[i][ks], bf[j][ks], acc[i][j], 0, 0, 0);            \
    } while (0)

    STAGE_B(0, 0);
    LOAD_A(0);
    FINISH_A(0);
    __syncthreads();

    int cur = 0;
    for (int t = 0; t < HD / 64; ++t) {
        if (t < HD / 64 - 1) {
            STAGE_B(cur ^ 1, (t + 1) * 64);   // async, drains at the barrier
            LOAD_A((t + 1) * 64);             // regs, consumed after MFMA
        }
        COMPUTE(cur);
        if (t < HD / 64 - 1) FINISH_A(cur ^ 1);
        __syncthreads();
        cur ^= 1;
    }

    if (do_gate) {
        // ---- gate epilogue + plain q store (exact R4 behavior) ----
        gacc0 += __shfl_xor(gacc0, 1);
        gacc0 += __shfl_xor(gacc0, 2);
        gacc0 += __shfl_xor(gacc0, 4);
        gacc1 += __shfl_xor(gacc1, 1);
        gacc1 += __shfl_xor(gacc1, 2);
        gacc1 += __shfl_xor(gacc1, 4);
        if ((tid & 7) == 0) {
            wg[row0 + ar0]      = 1.f / (1.f + expf(-(gacc0 + gb[0])));
            wg[row0 + ar0 + 32] = 1.f / (1.f + expf(-(gacc1 + gb[0])));
        }
        #pragma unroll
        for (int i = 0; i < 2; ++i) {
            int m = row0 + wm * 32 + i * 16 + (lane >> 4) * 4;
            #pragma unroll
            for (int j = 0; j < 4; ++j) {
                int c = wn * 64 + j * 16 + (lane & 15);
                #pragma unroll
                for (int r = 0; r < 4; ++r)
                    q[(size_t)(m + r) * MD + c] = acc[i][j][r];
            }
        }
    } else {
        // ---- fused l2norm epilogue for k (y=1) / v (y=2) ----
        // overlay 32 KB on Bs (all waves past the final barrier).
        float* t_s = (float*)&Bs[0][0];           // [64][128] f32
        #pragma unroll
        for (int i = 0; i < 2; ++i) {
            int m = wm * 32 + i * 16 + (lane >> 4) * 4;
            #pragma unroll
            for (int j = 0; j < 4; ++j) {
                int c = wn * 64 + j * 16 + (lane & 15);
                #pragma unroll
                for (int r = 0; r < 4; ++r)
                    t_s[(m + r) * 128 + c] = acc[i][j][r];
            }
        }
        __syncthreads();
        float* dst = (blockIdx.y == 1) ? k : v;
        // 16 rows per wave; EXACT normsig order: lane owns dims 2l, 2l+1,
        // ss = x0*x0 + x1*x1, full xor tree 32..1, inv = 1/max(sqrt,1e-12).
        #pragma unroll
        for (int rr = 0; rr < 16; ++rr) {
            int row = wave * 16 + rr;
            float x0 = t_s[row * 128 + 2 * lane];
            float x1 = t_s[row * 128 + 2 * lane + 1];
            float ss = x0 * x0 + x1 * x1;
            #pragma unroll
            for (int off = 32; off > 0; off >>= 1) ss += __shfl_xor(ss, off);
            float inv = 1.f / fmaxf(sqrtf(ss), 1e-12f);
            float2 o; o.x = x0 * inv; o.y = x1 * inv;
            *(float2*)&dst[(size_t)(row0 + row) * MD + 2 * lane] = o;
        }
    }
#undef STAGE_B
#undef LOAD_A
#undef FINISH_A
#undef COMPUTE
}

// ---------------------------------------------------------------------------
// K2a: per-(chunk,batch) partial aggregation. grid 256 = chunk*4 + batch.
// ---------------------------------------------------------------------------
__global__ __launch_bounds__(256) void agg_part_kernel(
    const float* __restrict__ kn, const float* __restrict__ vn,
    const float* __restrict__ w,
    float* __restrict__ kpart, float* __restrict__ vpart,
    float* __restrict__ wpart)
{
    int t = blockIdx.x >> 2, b = blockIdx.x & 3;
    int tid = threadIdx.x;
    int d = tid & 127, h = tid >> 7;
    int base_row = b * SEQ + t * CHK;

    float ka = 0.f, va = 0.f;
    for (int c = h * 32; c < h * 32 + 32; ++c) {
        int row = base_row + c;
        float wv = w[row];
        ka = fmaf(wv, kn[(size_t)row * MD + d], ka);
        va = fmaf(wv, vn[(size_t)row * MD + d], va);
    }
    __shared__ float sk[128], sv[128];
    if (h == 1) { sk[d] = ka; sv[d] = va; }
    __syncthreads();
    if (h == 0) {
        kpart[(size_t)blockIdx.x * 128 + d] = ka + sk[d];
        vpart[(size_t)blockIdx.x * 128 + d] = va + sv[d];
    }
    if (tid < 64) {
        float wv = w[base_row + tid];
        #pragma unroll
        for (int off = 32; off > 0; off >>= 1) wv += __shfl_xor(wv, off);
        if (tid == 0) wpart[blockIdx.x] = wv;
    }
}

// ---------------------------------------------------------------------------
// K2b: combine partials per chunk, normalize, emit kaT / vagg / wstr.
// grid 64, 128 threads (2 waves)
// ---------------------------------------------------------------------------
__global__ __launch_bounds__(128) void agg_combine_kernel(
    const float* __restrict__ kpart, const float* __restrict__ vpart,
    const float* __restrict__ wpart,
    float* __restrict__ kaT, float* __restrict__ vagg, float* __restrict__ wstr)
{
    int t = blockIdx.x;
    int d = threadIdx.x;              // 0..127
    int wave = d >> 6, lane = d & 63;
    float ku = 0.f, vu = 0.f;
    #pragma unroll
    for (int b = 0; b < 4; ++b) {
        ku += kpart[(size_t)(t * 4 + b) * 128 + d];
        vu += vpart[(size_t)(t * 4 + b) * 128 + d];
    }
    float wsum = wpart[t * 4] + wpart[t * 4 + 1] + wpart[t * 4 + 2] + wpart[t * 4 + 3];
    float winv = 1.f / fmaxf(wsum, 1e-8f);
    ku *= winv; vu *= winv;

    __shared__ float red[4];
    float ks = ku * ku, vs = vu * vu;
    #pragma unroll
    for (int off = 32; off > 0; off >>= 1) {
        ks += __shfl_xor(ks, off);
        vs += __shfl_xor(vs, off);
    }
    if (lane == 0) { red[wave] = ks; red[2 + wave] = vs; }
    __syncthreads();
    float kinv = 1.f / fmaxf(sqrtf(red[0] + red[1]), 1e-12f);
    float vinv = 1.f / fmaxf(sqrtf(red[2] + red[3]), 1e-12f);
    kaT[d * NCH + t] = ku * kinv;
    vagg[t * MD + d] = vu * vinv;
    if (d == 0) wstr[t] = wsum * (1.f / 256.f);
}

// ---------------------------------------------------------------------------
// K2c: mean_ws -> last element of d_out
// ---------------------------------------------------------------------------
__global__ __launch_bounds__(64) void meanws_kernel(
    const float* __restrict__ wstr, float* __restrict__ outp)
{
    int lane = threadIdx.x;
    float v = wstr[lane];
    #pragma unroll
    for (int off = 32; off > 0; off >>= 1) v += __shfl_xor(v, off);
    if (lane == 0) outp[0] = v * (1.f / 64.f);
}

// ---------------------------------------------------------------------------
// K3 v2: causal slot attention + G-norm scale; writes r (fp16) for out GEMM.
//   256 blocks (1/CU), 512 threads (8 waves), 64 rows/block; kaT+vagg+G
//   staged once into 128 KB LDS. Arithmetic order identical to v1.
// ---------------------------------------------------------------------------
__global__ __launch_bounds__(512, 1) void attn_kernel(
    const float* __restrict__ q, const float* __restrict__ kaT,
    const float* __restrict__ vagg, const float* __restrict__ G,
    const float* __restrict__ logbeta, _Float16* __restrict__ rsh16)
{
    __shared__ float kaT_s[MD * NCH];     // 32 KB [d][slot]
    __shared__ float vagg_s[NCH * MD];    // 32 KB [slot][d]
    __shared__ float G_s[MD * MD];        // 64 KB [b][d]
    __shared__ float qs[8][MD];           // 4 KB per-wave scratch
    __shared__ float attn_sh[8][64];      // 2 KB
    __shared__ float rsh_sh[8][MD];       // 4 KB   (total 138 KB)

    const int tid  = threadIdx.x;
    const int wave = tid >> 6, lane = tid & 63;
    const int row0 = blockIdx.x * 64;
    const int t = (row0 & (SEQ - 1)) >> 6;      // uniform for the whole block
    const float beta = expf(logbeta[0]);

    {
        const float4* s0 = (const float4*)kaT;
        const float4* s1 = (const float4*)vagg;
        const float4* s2 = (const float4*)G;
        float4* d0 = (float4*)kaT_s;
        float4* d1 = (float4*)vagg_s;
        float4* d2 = (float4*)G_s;
        #pragma unroll
        for (int i = 0; i < 4; ++i) {
            d0[tid + i * 512] = s0[tid + i * 512];
            d1[tid + i * 512] = s1[tid + i * 512];
        }
        #pragma unroll
        for (int i = 0; i < 8; ++i)
            d2[tid + i * 512] = s2[tid + i * 512];
    }
    __syncthreads();

    for (int rr = 0; rr < 8; ++rr) {
        const int row = row0 + wave * 8 + rr;
        float q0 = q[(size_t)row * MD + lane];
        float q1 = q[(size_t)row * MD + 64 + lane];
        qs[wave][lane]      = q0;
        qs[wave][lane + 64] = q1;   // wave-local: lgkmcnt ordering, no barrier

        float sc = -INFINITY;
        if (lane < t) {
            sc = 0.f;
            for (int d = 0; d < 128; ++d)
                sc = fmaf(qs[wave][d], kaT_s[d * NCH + lane], sc);
            sc *= beta;
        }
        float mx = sc;
        #pragma unroll
        for (int off = 32; off > 0; off >>= 1) mx = fmaxf(mx, __shfl_xor(mx, off));
        float e = (lane < t) ? expf(sc - mx) : 0.f;
        float ssum = e;
        #pragma unroll
        for (int off = 32; off > 0; off >>= 1) ssum += __shfl_xor(ssum, off);
        float attn = (t > 0) ? (e / ssum) : 0.f;
        attn_sh[wave][lane] = attn;

        float r0 = 0.f, r1 = 0.f;
        for (int n = 0; n < t; ++n) {
            float a = attn_sh[wave][n];
            r0 = fmaf(a, vagg_s[n * MD + lane], r0);
            r1 = fmaf(a, vagg_s[n * MD + 64 + lane], r1);
        }
        rsh_sh[wave][lane]      = r0;
        rsh_sh[wave][lane + 64] = r1;

        float t0 = 0.f, t1 = 0.f;
        for (int b = 0; b < 128; ++b) {
            float rb = rsh_sh[wave][b];
            t0 = fmaf(G_s[b * MD + lane], rb, t0);
            t1 = fmaf(G_s[b * MD + 64 + lane], rb, t1);
        }
        float quad = r0 * t0 + r1 * t1;
        #pragma unroll
        for (int off = 32; off > 0; off >>= 1) quad += __shfl_xor(quad, off);
        float nrm = fmaxf(sqrtf(fmaxf(quad, 0.f)), 1e-6f);
        float scl = fminf(10.f / nrm, 1.f);
        rsh16[(size_t)row * MD + lane]      = (_Float16)(r0 * scl);
        rsh16[(size_t)row * MD + 64 + lane] = (_Float16)(r1 * scl);
    }
}

// ---------------------------------------------------------------------------
// K4 v2: out = rsh16 @ Woh^T  (16384x128)@(2048x128)^T -> f32 (16384x2048)
//   Single-shot K=128, one barrier, swizzled via pre-swizzled global source.
// grid (128, 16), 256 threads
// ---------------------------------------------------------------------------
__global__ __launch_bounds__(256) void gemm_out_mfma(
    const _Float16* __restrict__ rsh16, const _Float16* __restrict__ Woh,
    float* __restrict__ C)
{
    __shared__ _Float16 As[128 * 128];   // 32 KB, 256 B rows, swizzled slots
    __shared__ _Float16 Bs[128 * 128];   // 32 KB
    floatx4 acc[4][4];
    #pragma unroll
    for (int i = 0; i < 4; ++i)
        #pragma unroll
        for (int j = 0; j < 4; ++j) acc[i][j] = (floatx4){0.f, 0.f, 0.f, 0.f};

    const int tid  = threadIdx.x;
    const int wave = tid >> 6, lane = tid & 63;
    const int wm = wave & 1, wn = wave >> 1;
    const int row0 = blockIdx.x * 128;
    const int col0 = blockIdx.y * 128;

    const int sr = lane >> 4;            // row within 4-row segment
    const int sp = lane & 15;            // physical 16B slot
    #pragma unroll
    for (int rnd = 0; rnd < 8; ++rnd) {
        int seg = wave * 8 + rnd;        // 0..31 (4 rows each)
        int r = seg * 4 + sr;            // 0..127
        int c = sp ^ (r & 15);           // source slot (swizzle pre-applied)
        gload_lds16(rsh16 + (size_t)(row0 + r) * MD + c * 8,
                    (char*)As + seg * 1024);
        gload_lds16(Woh + (size_t)(col0 + r) * MD + c * 8,
                    (char*)Bs + seg * 1024);
    }
    __syncthreads();

    #pragma unroll
    for (int kf = 0; kf < 4; ++kf) {
        half8 af[4], bf[4];
        #pragma unroll
        for (int i = 0; i < 4; ++i) {
            int r = wm * 64 + i * 16 + (lane & 15);
            int g = kf * 4 + (lane >> 4);
            af[i] = *(const half8*)((const char*)As + r * 256 + ((g ^ (r & 15)) * 16));
        }
        #pragma unroll
        for (int j = 0; j < 4; ++j) {
            int r = wn * 64 + j * 16 + (lane & 15);
            int g = kf * 4 + (lane >> 4);
            bf[j] = *(const half8*)((const char*)Bs + r * 256 + ((g ^ (r & 15)) * 16));
        }
        #pragma unroll
        for (int i = 0; i < 4; ++i)
            #pragma unroll
            for (int j = 0; j < 4; ++j)
                acc[i][j] = __builtin_amdgcn_mfma_f32_16x16x32_f16(
                    af[i], bf[j], acc[i][j], 0, 0, 0);
    }

    #pragma unroll
    for (int i = 0; i < 4; ++i) {
        int m = row0 + wm * 64 + i * 16 + (lane >> 4) * 4;
        #pragma unroll
        for (int j = 0; j < 4; ++j) {
            int c = col0 + wn * 64 + j * 16 + (lane & 15);
            #pragma unroll
            for (int r = 0; r < 4; ++r)
                C[(size_t)(m + r) * HD + c] = acc[i][j][r];
        }
    }
}

// ---------------------------------------------------------------------------
extern "C" void kernel_launch(void* const* d_in, const int* in_sizes, int n_in,
                              void* d_out, int out_size, void* d_ws, size_t ws_size,
                              hipStream_t stream)
{
    const float* x   = (const float*)d_in[0];   // (4,4096,2048)
    const float* Wq  = (const float*)d_in[1];   // (128,2048)
    const float* Wk  = (const float*)d_in[2];
    const float* Wv  = (const float*)d_in[3];
    const float* Wo  = (const float*)d_in[4];   // (2048,128)
    const float* Wgw = (const float*)d_in[5];   // (1,2048)
    const float* Wgb = (const float*)d_in[6];   // (1,)
    const float* lb  = (const float*)d_in[7];   // (1,)
    float* out = (float*)d_out;                 // 16384*2048 + 1

    // workspace layout (16B-aligned throughout)
    float* q    = (float*)d_ws;                            // 2,097,152 f32
    float* kn   = q + (size_t)NTOK * MD;                   // normalized k
    float* vn   = kn + (size_t)NTOK * MD;                  // normalized v
    float* wg   = vn + (size_t)NTOK * MD;                  // 16384
    float* kaT  = wg + NTOK;                               // 8192
    float* vagg = kaT + MD * NCH;                          // 8192
    float* wstr = vagg + NCH * MD;                         // 64
    float* G    = wstr + 64;                               // 16384
    float* kpart = G + MD * MD;                            // 32768
    float* vpart = kpart + 256 * 128;                      // 32768
    float* wpart = vpart + 256 * 128;                      // 256
    _Float16* Wcath = (_Float16*)(wpart + 256);            // 786,432 fp16
    _Float16* Woh   = Wcath + 384 * HD;                    // 262,144 fp16
    _Float16* rsh16 = Woh + HD * MD;                       // 2,097,152 fp16

    convert_w_kernel<<<dim3(4096), dim3(256), 0, stream>>>(Wq, Wk, Wv, Wo, Wcath, Woh);
    gmat_kernel<<<dim3(128), dim3(128), 0, stream>>>(Wo, G);
    gemm_proj_mfma<<<dim3(NTOK / 64, 3), dim3(256), 0, stream>>>(
        x, Wcath, Wgw, Wgb, q, kn, vn, wg);
    agg_part_kernel<<<dim3(256), dim3(256), 0, stream>>>(kn, vn, wg, kpart, vpart, wpart);
    agg_combine_kernel<<<dim3(NCH), dim3(128), 0, stream>>>(kpart, vpart, wpart, kaT, vagg, wstr);
    meanws_kernel<<<dim3(1), dim3(64), 0, stream>>>(wstr, out + (size_t)NTOK * HD);
    attn_kernel<<<dim3(NTOK / 64), dim3(512), 0, stream>>>(q, kaT, vagg, G, lb, rsh16);
    gemm_out_mfma<<<dim3(NTOK / 128, HD / 128), dim3(256), 0, stream>>>(rsh16, Woh, out);
}